// Round 5
// baseline (124.668 us; speedup 1.0000x reference)
//
#include <hip/hip_runtime.h>
#include <hip/hip_fp16.h>
#include <cmath>

#define DF 128            // feature dim
#define WPITCHH 136       // LDS W row pitch in halves (128 + 8 pad, 272 B)

typedef _Float16 f16x8 __attribute__((ext_vector_type(8)));
typedef _Float16 f16x4 __attribute__((ext_vector_type(4)));
typedef float    f32x4 __attribute__((ext_vector_type(4)));

// ---------------------------------------------------------------------------
// Kernel A: fused {edge-meta build + CSR rowptr} + {support GEMM via MFMA}.
// (R4 note: cooperative single-kernel fusion FAILED on this harness — the
// launch is rejected / never runs. Two-kernel structure is the ceiling.)
// X is loaded NON-TEMPORAL: it is read exactly once, and keeping it out of
// L2 preserves residency for S, which the agg phase re-reads ~12x per row.
// ---------------------------------------------------------------------------
__global__ __launch_bounds__(256)
void gemm_meta_kernel(const float* __restrict__ X, const float* __restrict__ W,
                      const float* __restrict__ bias, __half* __restrict__ S,
                      const int* __restrict__ arow, const int* __restrict__ acol,
                      const float* __restrict__ aval,
                      int* __restrict__ rowptr, int2* __restrict__ pk,
                      int N, int E, int nthreads)
{
    __shared__ _Float16 Wl[DF * WPITCHH];          // 34 KB

    const int t   = threadIdx.x;
    const int tid = blockIdx.x * 256 + t;

    // ---- meta: packed edge {byte_offset, val_bits} + CSR rowptr ----
    for (int e = tid; e < E; e += nthreads) {
        pk[e] = make_int2(acol[e] << 8, __float_as_int(aval[e]));
        int r     = arow[e];
        int rprev = (e == 0) ? -1 : arow[e - 1];
        for (int n = rprev + 1; n <= r; ++n) rowptr[n] = e;
        if (e == E - 1) {
            for (int n = r + 1; n <= N; ++n) rowptr[n] = E;
        }
    }

    // ---- stage W into LDS, converting fp32 -> fp16 in flight ----
    #pragma unroll
    for (int l = 0; l < 8; ++l) {
        int flat = l * 256 + t;                    // 0..2047
        int r    = flat >> 4;                      // 0..127
        int c8   = (flat & 15) * 8;                // 0..120
        const float* wp = W + (size_t)r * DF + c8;
        float4 wa = *(const float4*)wp;
        float4 wb = *(const float4*)(wp + 4);
        f16x8 v;
        v[0] = (_Float16)wa.x; v[1] = (_Float16)wa.y;
        v[2] = (_Float16)wa.z; v[3] = (_Float16)wa.w;
        v[4] = (_Float16)wb.x; v[5] = (_Float16)wb.y;
        v[6] = (_Float16)wb.z; v[7] = (_Float16)wb.w;
        *(f16x8*)(Wl + r * WPITCHH + c8) = v;
    }
    __syncthreads();

    const int lane = t & 63;
    const int l15  = lane & 15;
    const int q    = lane >> 4;                    // 0..3
    const int m0   = (blockIdx.x * 4 + (t >> 6)) * 16;
    if (m0 >= N) return;

    f32x4 acc[8];
    #pragma unroll
    for (int nt = 0; nt < 8; ++nt) acc[nt] = (f32x4){0.f, 0.f, 0.f, 0.f};

    const int xrow = min(m0 + l15, N - 1);         // clamp (dup read) for tail
    #pragma unroll
    for (int kc = 0; kc < DF; kc += 32) {
        const float* xp = X + (size_t)xrow * DF + kc + q * 8;
        f32x4 xa = __builtin_nontemporal_load((const f32x4*)xp);
        f32x4 xb = __builtin_nontemporal_load((const f32x4*)(xp + 4));
        f16x8 A;
        A[0] = (_Float16)xa[0]; A[1] = (_Float16)xa[1];
        A[2] = (_Float16)xa[2]; A[3] = (_Float16)xa[3];
        A[4] = (_Float16)xb[0]; A[5] = (_Float16)xb[1];
        A[6] = (_Float16)xb[2]; A[7] = (_Float16)xb[3];
        #pragma unroll
        for (int nt = 0; nt < 8; ++nt) {
            f16x8 B = *(const f16x8*)(Wl + (nt * 16 + l15) * WPITCHH + kc + q * 8);
            // swapped: first operand = W rows (o), second = X rows (node)
            acc[nt] = __builtin_amdgcn_mfma_f32_16x16x32_f16(B, A, acc[nt], 0, 0, 0);
        }
    }

    const int mrow = m0 + l15;
    if (mrow < N) {
        _Float16* rowp = (_Float16*)S + (size_t)mrow * DF;
        #pragma unroll
        for (int nt = 0; nt < 8; ++nt) {
            float4 bv = *(const float4*)(bias + nt * 16 + q * 4);
            f16x4 hv;
            hv[0] = (_Float16)(acc[nt][0] + bv.x);
            hv[1] = (_Float16)(acc[nt][1] + bv.y);
            hv[2] = (_Float16)(acc[nt][2] + bv.z);
            hv[3] = (_Float16)(acc[nt][3] + bv.w);
            *(f16x4*)(rowp + nt * 16 + q * 4) = hv;
        }
    }
}

// ---------------------------------------------------------------------------
// exp-based tanh: 1 - 2/(e^{2x}+1). Abs err ~1e-6 (<< fp16 quantization
// already present in S). Proven absmax-neutral in R3.
// ---------------------------------------------------------------------------
__device__ __forceinline__ float tanh_fast(float x)
{
    float e = __expf(2.0f * x);
    return 1.0f - 2.0f / (e + 1.0f);
}

// ---------------------------------------------------------------------------
// Kernel B: out[n][:] = tanh( sum_e val[e]*S_fp16[col[e]][:] ) per CSR row.
// ONE 16-LANE GROUP PER NODE (proven; R1 showed more-waves/less-work
// regresses). 8-edge unroll + branchless tail (R3, neutral but kept).
// OUT stores are NON-TEMPORAL: out is never re-read, and bypassing L2
// preserves residency for the S gather stream.
// ---------------------------------------------------------------------------
__global__ __launch_bounds__(256)
void agg_tanh_kernel(const __half* __restrict__ S, const int* __restrict__ rowptr,
                     const int2* __restrict__ pk, float* __restrict__ out, int Nn)
{
    const int n  = (blockIdx.x * 256 + threadIdx.x) >> 4;   // node = global group
    if (n >= Nn) return;
    const int f  = threadIdx.x & 15;                        // feature chunk
    const int fb = f * 16;                                  // byte offset in row

    const int start = rowptr[n];
    const int end   = rowptr[n + 1];
    const char* Sb  = (const char*)S;

    float acc[8];
    #pragma unroll
    for (int i = 0; i < 8; ++i) acc[i] = 0.f;

    const int last = end - 1;
    for (int e = start; e < end; e += 8) {
        int2 p0 = pk[min(e    , last)];
        int2 p1 = pk[min(e + 1, last)];
        int2 p2 = pk[min(e + 2, last)];
        int2 p3 = pk[min(e + 3, last)];
        int2 p4 = pk[min(e + 4, last)];
        int2 p5 = pk[min(e + 5, last)];
        int2 p6 = pk[min(e + 6, last)];
        int2 p7 = pk[min(e + 7, last)];
        f16x8 h0 = *(const f16x8*)(Sb + (size_t)(unsigned)p0.x + fb);
        f16x8 h1 = *(const f16x8*)(Sb + (size_t)(unsigned)p1.x + fb);
        f16x8 h2 = *(const f16x8*)(Sb + (size_t)(unsigned)p2.x + fb);
        f16x8 h3 = *(const f16x8*)(Sb + (size_t)(unsigned)p3.x + fb);
        f16x8 h4 = *(const f16x8*)(Sb + (size_t)(unsigned)p4.x + fb);
        f16x8 h5 = *(const f16x8*)(Sb + (size_t)(unsigned)p5.x + fb);
        f16x8 h6 = *(const f16x8*)(Sb + (size_t)(unsigned)p6.x + fb);
        f16x8 h7 = *(const f16x8*)(Sb + (size_t)(unsigned)p7.x + fb);
        const float v0 = __int_as_float(p0.y);
        const float v1 = (e + 1 < end) ? __int_as_float(p1.y) : 0.f;
        const float v2 = (e + 2 < end) ? __int_as_float(p2.y) : 0.f;
        const float v3 = (e + 3 < end) ? __int_as_float(p3.y) : 0.f;
        const float v4 = (e + 4 < end) ? __int_as_float(p4.y) : 0.f;
        const float v5 = (e + 5 < end) ? __int_as_float(p5.y) : 0.f;
        const float v6 = (e + 6 < end) ? __int_as_float(p6.y) : 0.f;
        const float v7 = (e + 7 < end) ? __int_as_float(p7.y) : 0.f;
        #pragma unroll
        for (int i = 0; i < 8; ++i) {
            acc[i] += (float)h0[i] * v0 + (float)h1[i] * v1
                    + (float)h2[i] * v2 + (float)h3[i] * v3
                    + (float)h4[i] * v4 + (float)h5[i] * v5
                    + (float)h6[i] * v6 + (float)h7[i] * v7;
        }
    }

    f32x4 o0, o1;
    o0[0] = tanh_fast(acc[0]); o0[1] = tanh_fast(acc[1]);
    o0[2] = tanh_fast(acc[2]); o0[3] = tanh_fast(acc[3]);
    o1[0] = tanh_fast(acc[4]); o1[1] = tanh_fast(acc[5]);
    o1[2] = tanh_fast(acc[6]); o1[3] = tanh_fast(acc[7]);
    float* op = out + (size_t)n * DF + f * 8;
    __builtin_nontemporal_store(o0, (f32x4*)op);
    __builtin_nontemporal_store(o1, (f32x4*)(op + 4));
}

// ---------------------------------------------------------------------------
extern "C" void kernel_launch(void* const* d_in, const int* in_sizes, int n_in,
                              void* d_out, int out_size, void* d_ws, size_t ws_size,
                              hipStream_t stream)
{
    const float* X    = (const float*)d_in[0];   // [N, 128]
    const float* W    = (const float*)d_in[1];   // [128, 128]
    const float* bias = (const float*)d_in[2];   // [128]
    const int*   arow = (const int*)  d_in[3];   // [E] sorted
    const int*   acol = (const int*)  d_in[4];   // [E]
    const float* aval = (const float*)d_in[5];   // [E]
    float* out = (float*)d_out;

    const int N = in_sizes[0] / DF;
    const int E = in_sizes[3];

    // ws layout: S [N*128 fp16] | rowptr [N+2] | pk [E int2]
    __half* S      = (__half*)d_ws;
    int*    rowptr = (int*)((char*)d_ws + (size_t)N * DF * sizeof(__half));
    int2*   pk     = (int2*)(rowptr + (N + 2));

    const int gemmBlocks = (N + 63) / 64;
    gemm_meta_kernel<<<gemmBlocks, 256, 0, stream>>>(X, W, bias, S,
                                                     arow, acol, aval,
                                                     rowptr, pk, N, E,
                                                     gemmBlocks * 256);

    agg_tanh_kernel<<<(N * 16 + 255) / 256, 256, 0, stream>>>(S, rowptr, pk, out, N);
}